// Round 5
// baseline (191.888 us; speedup 1.0000x reference)
//
#include <hip/hip_runtime.h>

// Problem constants (from reference: shape (32,1,512,512) fp32)
#define BATCH 32
#define H 512
#define W 512
#define N_TOT (BATCH * H * W)   // 8388608

// No-LDS streaming kernel, single-latency-round version.
// Each thread owns an 8-wide x 2-tall output patch; a wave's 64 lanes span
// the full 512-px row (halo via __shfl; lane edge == image edge == zero-pad).
// ALL 24 float4 loads (3 images x 4 rows x 2) are issued up-front into a
// register array, then everything (l_loss + 3 sobels + fold) is computed from
// registers -- one memory-latency exposure per wave instead of round-4's ~6
// sequential load->shfl->compute rounds. l_loss reuses the sobel center rows
// (no extra loads).

__device__ __forceinline__ float f4get(const float4& v, int i) {
    switch (i & 3) {
        case 0:  return v.x;
        case 1:  return v.y;
        case 2:  return v.z;
        default: return v.w;
    }
}

__global__ __launch_bounds__(256)
void fusion_loss_kernel(const float* __restrict__ A,
                        const float* __restrict__ B,
                        const float* __restrict__ F,
                        const int* __restrict__ scheme_arr,
                        float* __restrict__ out)
{
    __shared__ float red[4];

    const int t   = threadIdx.x;
    const int tx  = t & 63;                  // lane: column group (8 px each)
    const int ty  = t >> 6;                  // wave: row pair 0..3
    const int b   = blockIdx.y;
    const int x0  = tx << 3;
    const int y0  = (blockIdx.x << 3) + (ty << 1);
    const int base = b * (H * W);
    const int scheme = scheme_arr[b];

    // ---- load phase: 24 independent float4 loads, all issued before use ----
    float4 v[3][4][2];
    const float* __restrict__ imgs[3] = {A, B, F};
#pragma unroll
    for (int im = 0; im < 3; ++im) {
#pragma unroll
        for (int rr = 0; rr < 4; ++rr) {
            const int yy = y0 - 1 + rr;
            const bool rv = (unsigned)yy < (unsigned)H;   // wave-uniform
            const float* row = imgs[im] + base + yy * W + x0;
            const float4 z = make_float4(0.f, 0.f, 0.f, 0.f);
            v[im][rr][0] = rv ? *reinterpret_cast<const float4*>(row)     : z;
            v[im][rr][1] = rv ? *reinterpret_cast<const float4*>(row + 4) : z;
        }
    }

    float acc = 0.f;

    // ---- l_loss: center rows rr=1,2 are output rows y0,y0+1 (in-bounds) ----
#pragma unroll
    for (int rr = 1; rr <= 2; ++rr)
#pragma unroll
        for (int hf = 0; hf < 2; ++hf)
#pragma unroll
            for (int c = 0; c < 4; ++c) {
                const float av = f4get(v[0][rr][hf], c);
                const float bv = f4get(v[1][rr][hf], c);
                const float fv = f4get(v[2][rr][hf], c);
                const float ab = (scheme == 0) ? 0.5f * (av + bv)
                               : (scheme == 1) ? fmaxf(av, bv)
                               : 0.f;
                acc += fabsf(ab - fv);
            }

    // ---- grad_loss: per-image separable sobel from registers ----
    float sobM[2][8];
#pragma unroll
    for (int im = 0; im < 3; ++im) {
        float h1[4][8], h2[4][8];
#pragma unroll
        for (int rr = 0; rr < 4; ++rr) {
            const float4 s1 = v[im][rr][0];
            const float4 s2 = v[im][rr][1];
            float lw = __shfl_up(s2.w, 1, 64);    // lane tx-1's col x0-1
            if (tx == 0)  lw = 0.f;               // image left edge
            float rw = __shfl_down(s1.x, 1, 64);  // lane tx+1's col x0+8
            if (tx == 63) rw = 0.f;               // image right edge
            const float vv[10] = {lw, s1.x, s1.y, s1.z, s1.w,
                                  s2.x, s2.y, s2.z, s2.w, rw};
#pragma unroll
            for (int c = 0; c < 8; ++c) {
                h1[rr][c] = vv[c + 2] - vv[c];                     // [-1,0,1]
                h2[rr][c] = vv[c] + 2.f * vv[c + 1] + vv[c + 2];   // [1,2,1]
            }
        }
#pragma unroll
        for (int o = 0; o < 2; ++o)
#pragma unroll
            for (int c = 0; c < 8; ++c) {
                const float gx = h1[o][c] + 2.f * h1[o + 1][c] + h1[o + 2][c];
                const float gy = h2[o][c] - h2[o + 2][c];
                const float sob = fabsf(gx) + fabsf(gy);
                if (im == 0)      sobM[o][c] = sob;
                else if (im == 1) sobM[o][c] = fmaxf(sobM[o][c], sob);
                else              acc += fabsf(sob - sobM[o][c]);
            }
    }

    // ---- reduction: 64-lane shuffle, cross-wave via LDS, one atomic ----
#pragma unroll
    for (int off = 32; off > 0; off >>= 1)
        acc += __shfl_down(acc, off, 64);
    if ((t & 63) == 0) red[t >> 6] = acc;
    __syncthreads();
    if (t == 0)
        atomicAdd(out, (red[0] + red[1] + red[2] + red[3]) * (1.0f / (float)N_TOT));
}

extern "C" void kernel_launch(void* const* d_in, const int* in_sizes, int n_in,
                              void* d_out, int out_size, void* d_ws, size_t ws_size,
                              hipStream_t stream)
{
    const float* A = (const float*)d_in[0];
    const float* B = (const float*)d_in[1];
    const float* F = (const float*)d_in[2];
    const int* scheme = (const int*)d_in[3];
    float* out = (float*)d_out;

    // d_out is poisoned before every launch; zero it for the atomics.
    hipMemsetAsync(out, 0, sizeof(float), stream);

    dim3 grid(H / 8, BATCH);   // 64 row-slabs x 32 batches = 2048 blocks
    dim3 block(256);
    fusion_loss_kernel<<<grid, block, 0, stream>>>(A, B, F, scheme, out);
}

// Round 6
// 191.285 us; speedup vs baseline: 1.0032x; 1.0032x over previous
//
#include <hip/hip_runtime.h>

// Problem constants (from reference: shape (32,1,512,512) fp32)
#define BATCH 32
#define H 512
#define W 512
#define N_TOT (BATCH * H * W)   // 8388608

// No-LDS streaming kernel, single-latency-round version.
// Each thread owns an 8-wide x 2-tall output patch; a wave's 64 lanes span
// the full 512-px row (halo via __shfl; lane edge == image edge == zero-pad).
// ALL 24 float4 loads (3 images x 4 rows x 2) are issued up-front into
// registers, then everything is computed from registers.
//
// __launch_bounds__(256, 2): round 5 showed that without an explicit budget
// the allocator targets high occupancy (68 VGPRs) and spills the load batch
// to scratch (8.4 MB of scratch writes). 2 waves/EU -> 256 VGPR budget; the
// ~180-reg live set fits with zero spill. 8 waves/CU x 24 loads in flight
// (~25 KB/wave) >> the ~9 KB/CU needed to cover HBM latency.

__global__ __launch_bounds__(256, 2)
void fusion_loss_kernel(const float* __restrict__ A,
                        const float* __restrict__ B,
                        const float* __restrict__ F,
                        const int* __restrict__ scheme_arr,
                        float* __restrict__ out)
{
    __shared__ float red[4];

    const int t   = threadIdx.x;
    const int tx  = t & 63;                  // lane: column group (8 px each)
    const int ty  = t >> 6;                  // wave: row pair 0..3
    const int b   = blockIdx.y;
    const int x0  = tx << 3;
    const int y0  = (blockIdx.x << 3) + (ty << 1);
    const int base = b * (H * W);
    const int scheme = scheme_arr[b];

    // ---- load phase: 24 independent float4 loads, all issued before use.
    //      Order A rows, B rows, F rows so compute on A can start under a
    //      partial vmcnt wait while B/F are still in flight. ----
    float4 s1[3][4], s2[3][4];
    const float* __restrict__ imgs[3] = {A, B, F};
#pragma unroll
    for (int im = 0; im < 3; ++im) {
#pragma unroll
        for (int rr = 0; rr < 4; ++rr) {
            const int yy = y0 - 1 + rr;
            const bool rv = (unsigned)yy < (unsigned)H;   // wave-uniform
            const float* row = imgs[im] + base + yy * W + x0;
            const float4 z = make_float4(0.f, 0.f, 0.f, 0.f);
            s1[im][rr] = rv ? *reinterpret_cast<const float4*>(row)     : z;
            s2[im][rr] = rv ? *reinterpret_cast<const float4*>(row + 4) : z;
        }
    }

    float acc = 0.f;
    float sobM[2][8];

    // ---- grad_loss: per-image separable sobel from registers (A, B, then F) ----
#pragma unroll
    for (int im = 0; im < 3; ++im) {
        float h1[4][8], h2[4][8];
#pragma unroll
        for (int rr = 0; rr < 4; ++rr) {
            const float4 a = s1[im][rr];
            const float4 c = s2[im][rr];
            float lw = __shfl_up(c.w, 1, 64);    // lane tx-1's col x0-1
            if (tx == 0)  lw = 0.f;              // image left edge
            float rw = __shfl_down(a.x, 1, 64);  // lane tx+1's col x0+8
            if (tx == 63) rw = 0.f;              // image right edge
            const float vv[10] = {lw, a.x, a.y, a.z, a.w,
                                  c.x, c.y, c.z, c.w, rw};
#pragma unroll
            for (int cc = 0; cc < 8; ++cc) {
                h1[rr][cc] = vv[cc + 2] - vv[cc];                      // [-1,0,1]
                h2[rr][cc] = vv[cc] + 2.f * vv[cc + 1] + vv[cc + 2];   // [1,2,1]
            }
        }
#pragma unroll
        for (int o = 0; o < 2; ++o)
#pragma unroll
            for (int cc = 0; cc < 8; ++cc) {
                const float gx = h1[o][cc] + 2.f * h1[o + 1][cc] + h1[o + 2][cc];
                const float gy = h2[o][cc] - h2[o + 2][cc];
                const float sob = fabsf(gx) + fabsf(gy);
                if (im == 0)      sobM[o][cc] = sob;
                else if (im == 1) sobM[o][cc] = fmaxf(sobM[o][cc], sob);
                else              acc += fabsf(sob - sobM[o][cc]);
            }
    }

    // ---- l_loss: center rows rr=1,2 are output rows y0,y0+1 (in-bounds);
    //      explicit components, no dynamic indexing ----
#pragma unroll
    for (int rr = 1; rr <= 2; ++rr) {
#pragma unroll
        for (int hf = 0; hf < 2; ++hf) {
            const float4 av4 = hf ? s2[0][rr] : s1[0][rr];
            const float4 bv4 = hf ? s2[1][rr] : s1[1][rr];
            const float4 fv4 = hf ? s2[2][rr] : s1[2][rr];
            const float av[4] = {av4.x, av4.y, av4.z, av4.w};
            const float bv[4] = {bv4.x, bv4.y, bv4.z, bv4.w};
            const float fv[4] = {fv4.x, fv4.y, fv4.z, fv4.w};
#pragma unroll
            for (int c = 0; c < 4; ++c) {
                const float ab = (scheme == 0) ? 0.5f * (av[c] + bv[c])
                               : (scheme == 1) ? fmaxf(av[c], bv[c])
                               : 0.f;
                acc += fabsf(ab - fv[c]);
            }
        }
    }

    // ---- reduction: 64-lane shuffle, cross-wave via LDS, one atomic ----
#pragma unroll
    for (int off = 32; off > 0; off >>= 1)
        acc += __shfl_down(acc, off, 64);
    if ((t & 63) == 0) red[t >> 6] = acc;
    __syncthreads();
    if (t == 0)
        atomicAdd(out, (red[0] + red[1] + red[2] + red[3]) * (1.0f / (float)N_TOT));
}

extern "C" void kernel_launch(void* const* d_in, const int* in_sizes, int n_in,
                              void* d_out, int out_size, void* d_ws, size_t ws_size,
                              hipStream_t stream)
{
    const float* A = (const float*)d_in[0];
    const float* B = (const float*)d_in[1];
    const float* F = (const float*)d_in[2];
    const int* scheme = (const int*)d_in[3];
    float* out = (float*)d_out;

    // d_out is poisoned before every launch; zero it for the atomics.
    hipMemsetAsync(out, 0, sizeof(float), stream);

    dim3 grid(H / 8, BATCH);   // 64 row-slabs x 32 batches = 2048 blocks
    dim3 block(256);
    fusion_loss_kernel<<<grid, block, 0, stream>>>(A, B, F, scheme, out);
}

// Round 7
// 133.542 us; speedup vs baseline: 1.4369x; 1.4324x over previous
//
#include <hip/hip_runtime.h>

// Problem constants (from reference: shape (32,1,512,512) fp32)
#define BATCH 32
#define H 512
#define W 512
#define N_TOT (BATCH * H * W)   // 8388608
#define BAND 8                  // output rows per wave

// Streaming row-band kernel with rolling register reuse.
// Wave = 64 lanes x 4 px = half a 512-px row. Each wave owns BAND=8
// consecutive output rows of one image half and walks them with a 4-slot
// register ring (slot = row & 3; r0 is a multiple of 8, so every slot index
// is a compile-time constant after unrolling -> SROA keeps it in registers;
// rounds 3/5/6 showed any dynamic-ish batch gets spilled).
// Per iteration: issue the NEXT row's loads (3 float4 + 6 halo dwords, halo
// is an L1 hit), then compute the CURRENT output row from data loaded a full
// iteration ago -> per-wave load/compute overlap, plus 4 waves/SIMD (all
// 4096 waves co-resident) for cross-wave hiding. Rolling reuse cuts HBM
// traffic to 10 input rows per 8 output rows (1.25x).

__global__ __launch_bounds__(256)
void fusion_loss_kernel(const float* __restrict__ A,
                        const float* __restrict__ B,
                        const float* __restrict__ F,
                        const int* __restrict__ scheme_arr,
                        float* __restrict__ out)
{
    __shared__ float red[4];

    const int t    = threadIdx.x;
    const int lane = t & 63;
    const int ty   = t >> 6;
    const int wave = blockIdx.x * 4 + ty;      // 4096 waves total
    const int half = wave & 1;                 // left/right 256-px half
    const int band = wave >> 1;                // 2048 bands
    const int b    = band >> 6;                // batch (64 bands per image)
    const int r0   = (band & 63) << 3;         // first output row (mult of 8)
    const int x0   = (half << 8) + (lane << 2);
    const int base = b * (H * W);
    const int scheme = scheme_arr[b];
    const bool has_l = (x0 > 0);
    const bool has_r = (x0 + 4 < W);

    const float* __restrict__ imgs[3] = {A, B, F};

    // rolling ring: rc = center 4 px, rl/rh = 1-px halo each side
    float4 rc[3][4];
    float  rl[3][4];
    float  rh[3][4];

    auto load_row = [&](int y, int slot) {
        const bool rv = (unsigned)y < (unsigned)H;   // wave-uniform
#pragma unroll
        for (int im = 0; im < 3; ++im) {
            float4 c = make_float4(0.f, 0.f, 0.f, 0.f);
            float lf = 0.f, rt = 0.f;
            if (rv) {
                const float* row = imgs[im] + base + y * W;
                c  = *reinterpret_cast<const float4*>(row + x0);
                lf = has_l ? row[x0 - 1] : 0.f;   // L1 hit (neighbor's line)
                rt = has_r ? row[x0 + 4] : 0.f;   // L1 hit
            }
            rc[im][slot] = c;
            rl[im][slot] = lf;
            rh[im][slot] = rt;
        }
    };

    // preload rows r0-1, r0, r0+1 (slots 3, 0, 1; OOB rows load as zeros,
    // which is exactly the reference's zero padding)
    load_row(r0 - 1, 3);
    load_row(r0,     0);
    load_row(r0 + 1, 1);

    float acc = 0.f;

#pragma unroll
    for (int k = 0; k < BAND; ++k) {
        // prefetch row r0+k+2 into the slot holding dead row r0+k-2
        if (k < BAND - 1) load_row(r0 + k + 2, (k + 2) & 3);

        const int sm = (k + 3) & 3;   // row r0+k-1
        const int sc = k & 3;         // row r0+k
        const int sp = (k + 1) & 3;   // row r0+k+1

        float sobM[4];
#pragma unroll
        for (int im = 0; im < 3; ++im) {
            float gx[4], gy[4];
            {   // top row: gx = h1m, gy = h2m
                const float4 c4 = rc[im][sm];
                const float v[6] = {rl[im][sm], c4.x, c4.y, c4.z, c4.w, rh[im][sm]};
#pragma unroll
                for (int j = 0; j < 4; ++j) {
                    gx[j] = v[j + 2] - v[j];
                    gy[j] = v[j] + 2.f * v[j + 1] + v[j + 2];
                }
            }
            {   // center row: gx += 2*h1c
                const float4 c4 = rc[im][sc];
                const float v[6] = {rl[im][sc], c4.x, c4.y, c4.z, c4.w, rh[im][sc]};
#pragma unroll
                for (int j = 0; j < 4; ++j)
                    gx[j] += 2.f * (v[j + 2] - v[j]);
            }
            {   // bottom row: gx += h1p, gy -= h2p
                const float4 c4 = rc[im][sp];
                const float v[6] = {rl[im][sp], c4.x, c4.y, c4.z, c4.w, rh[im][sp]};
#pragma unroll
                for (int j = 0; j < 4; ++j) {
                    gx[j] += v[j + 2] - v[j];
                    gy[j] -= v[j] + 2.f * v[j + 1] + v[j + 2];
                }
            }
#pragma unroll
            for (int j = 0; j < 4; ++j) {
                const float sob = fabsf(gx[j]) + fabsf(gy[j]);
                if (im == 0)      sobM[j] = sob;
                else if (im == 1) sobM[j] = fmaxf(sobM[j], sob);
                else              acc += fabsf(sob - sobM[j]);
            }
        }

        // l_loss on the center row's 4 px (each pixel counted exactly once)
        {
            const float4 a4 = rc[0][sc], b4 = rc[1][sc], f4 = rc[2][sc];
            const float av[4] = {a4.x, a4.y, a4.z, a4.w};
            const float bv[4] = {b4.x, b4.y, b4.z, b4.w};
            const float fv[4] = {f4.x, f4.y, f4.z, f4.w};
#pragma unroll
            for (int j = 0; j < 4; ++j) {
                const float ab = (scheme == 0) ? 0.5f * (av[j] + bv[j])
                               : (scheme == 1) ? fmaxf(av[j], bv[j])
                               : 0.f;
                acc += fabsf(ab - fv[j]);
            }
        }
    }

    // ---- reduction: 64-lane shuffle, cross-wave via LDS, one atomic ----
#pragma unroll
    for (int off = 32; off > 0; off >>= 1)
        acc += __shfl_down(acc, off, 64);
    if (lane == 0) red[ty] = acc;
    __syncthreads();
    if (t == 0)
        atomicAdd(out, (red[0] + red[1] + red[2] + red[3]) * (1.0f / (float)N_TOT));
}

extern "C" void kernel_launch(void* const* d_in, const int* in_sizes, int n_in,
                              void* d_out, int out_size, void* d_ws, size_t ws_size,
                              hipStream_t stream)
{
    const float* A = (const float*)d_in[0];
    const float* B = (const float*)d_in[1];
    const float* F = (const float*)d_in[2];
    const int* scheme = (const int*)d_in[3];
    float* out = (float*)d_out;

    // d_out is poisoned before every launch; zero it for the atomics.
    hipMemsetAsync(out, 0, sizeof(float), stream);

    // 4096 waves = 2048 row-bands x 2 halves; 1024 blocks x 4 waves.
    dim3 grid(1024);
    dim3 block(256);
    fusion_loss_kernel<<<grid, block, 0, stream>>>(A, B, F, scheme, out);
}